// Round 1
// baseline (271.124 us; speedup 1.0000x reference)
//
#include <hip/hip_runtime.h>

#define NEG 0.2f

__device__ __forceinline__ float leaky(float x){ return x > 0.f ? x : NEG*x; }
__device__ __forceinline__ float sel4(float4 q, int head){
  float lo = (head & 1) ? q.y : q.x;
  float hi = (head & 1) ? q.w : q.z;
  return (head & 2) ? hi : lo;
}

// ---------------- K1: hf = h @ fcw^T (fp32), fused el/er ----------------
// grid.x = ceil(N/64) node groups, grid.y = 2 feature halves. 256 threads.
// LDS: fc half [64 feats][128 k] (quad-XOR-swizzled) + 4 waves * 16 h rows.
__global__ __launch_bounds__(256) void k_proj(
    const float* __restrict__ h, const float* __restrict__ fcw,
    const float* __restrict__ attn_l, const float* __restrict__ attn_r,
    float* __restrict__ hf, float* __restrict__ el, float* __restrict__ er, int N)
{
  __shared__ float fcs[64][128];
  __shared__ float hs[4][16][128];
  const int g = blockIdx.y;
  const int tid = threadIdx.x;
  // stage fc rows g*64 .. g*64+63, swizzle k-quads by (row>>2)&7
  for (int i = tid; i < 64*32; i += 256) {
    int f = i >> 5, q = i & 31;
    float4 w = *(const float4*)&fcw[(size_t)(g*64 + f)*128 + 4*q];
    *(float4*)&fcs[f][4*(q ^ ((f>>2)&7))] = w;
  }
  const int wave = tid >> 6, lane = tid & 63;
  const int fq = lane & 15, ng = lane >> 4;
  const int nb0 = blockIdx.x*64 + wave*16;
  // stage this wave's 16 h rows
  for (int t = lane; t < 16*32; t += 64) {
    int n = t >> 5, c = t & 31;
    int gn = nb0 + n; if (gn >= N) gn = N-1;
    *(float4*)&hs[wave][n][4*c] = *(const float4*)&h[(size_t)gn*128 + 4*c];
  }
  __syncthreads();

  float acc[4][4];
  #pragma unroll
  for (int j = 0; j < 4; ++j)
    #pragma unroll
    for (int i = 0; i < 4; ++i) acc[j][i] = 0.f;

  #pragma unroll 8
  for (int kk = 0; kk < 32; ++kk) {
    const int qc = 4*(kk ^ (fq & 7));
    float4 r0 = *(const float4*)&fcs[4*fq + 0][qc];
    float4 r1 = *(const float4*)&fcs[4*fq + 1][qc];
    float4 r2 = *(const float4*)&fcs[4*fq + 2][qc];
    float4 r3 = *(const float4*)&fcs[4*fq + 3][qc];
    #pragma unroll
    for (int j = 0; j < 4; ++j) {
      float4 hv = *(const float4*)&hs[wave][ng*4 + j][4*kk];
      acc[j][0] += hv.x*r0.x + hv.y*r0.y + hv.z*r0.z + hv.w*r0.w;
      acc[j][1] += hv.x*r1.x + hv.y*r1.y + hv.z*r1.z + hv.w*r1.w;
      acc[j][2] += hv.x*r2.x + hv.y*r2.y + hv.z*r2.z + hv.w*r2.w;
      acc[j][3] += hv.x*r3.x + hv.y*r3.y + hv.z*r3.z + hv.w*r3.w;
    }
  }

  const float4 al4 = *(const float4*)&attn_l[g*64 + 4*fq];
  const float4 ar4 = *(const float4*)&attn_r[g*64 + 4*fq];
  #pragma unroll
  for (int j = 0; j < 4; ++j) {
    int gn = nb0 + ng*4 + j;
    float4 o = make_float4(acc[j][0], acc[j][1], acc[j][2], acc[j][3]);
    float elp = o.x*al4.x + o.y*al4.y + o.z*al4.z + o.w*al4.w;
    float erp = o.x*ar4.x + o.y*ar4.y + o.z*ar4.z + o.w*ar4.w;
    elp += __shfl_xor(elp, 1); elp += __shfl_xor(elp, 2); elp += __shfl_xor(elp, 4);
    erp += __shfl_xor(erp, 1); erp += __shfl_xor(erp, 2); erp += __shfl_xor(erp, 4);
    if (gn < N) {
      *(float4*)&hf[(size_t)gn*128 + g*64 + 4*fq] = o;
      if ((lane & 7) == 0) {
        int head = g*2 + ((lane >> 3) & 1);
        el[(size_t)gn*4 + head] = elp;
        er[(size_t)gn*4 + head] = erp;
      }
    }
  }
}

// ---------------- CSR build ----------------
__global__ void k_hist(const int* __restrict__ dst, int* __restrict__ counts, int E) {
  int e = blockIdx.x*256 + threadIdx.x;
  if (e < E) atomicAdd(&counts[dst[e]], 1);
}

__global__ __launch_bounds__(256) void k_block_sums(const int* __restrict__ counts, int N, int* __restrict__ bsum) {
  __shared__ int tmp[256];
  int i = blockIdx.x*256 + threadIdx.x;
  tmp[threadIdx.x] = (i < N) ? counts[i] : 0;
  __syncthreads();
  for (int off = 128; off > 0; off >>= 1) {
    if (threadIdx.x < off) tmp[threadIdx.x] += tmp[threadIdx.x + off];
    __syncthreads();
  }
  if (threadIdx.x == 0) bsum[blockIdx.x] = tmp[0];
}

__global__ __launch_bounds__(256) void k_scan_partials(int* __restrict__ bsum, int nb) {
  __shared__ int tmp[256];
  int t = threadIdx.x;
  int v = (t < nb) ? bsum[t] : 0;
  tmp[t] = v;
  __syncthreads();
  for (int off = 1; off < 256; off <<= 1) {
    int x = (t >= off) ? tmp[t - off] : 0;
    __syncthreads();
    tmp[t] += x;
    __syncthreads();
  }
  if (t < nb) bsum[t] = tmp[t] - v;   // exclusive prefix of block sums
}

__global__ __launch_bounds__(256) void k_scan_chunks(const int* __restrict__ counts, int N,
    const int* __restrict__ bsum, int* __restrict__ offsets, int* __restrict__ cursor) {
  __shared__ int tmp[256];
  int t = threadIdx.x;
  int i = blockIdx.x*256 + t;
  int v = (i < N) ? counts[i] : 0;
  tmp[t] = v;
  __syncthreads();
  for (int off = 1; off < 256; off <<= 1) {
    int x = (t >= off) ? tmp[t - off] : 0;
    __syncthreads();
    tmp[t] += x;
    __syncthreads();
  }
  if (i < N) {
    int excl = tmp[t] - v + bsum[blockIdx.x];
    offsets[i] = excl;
    cursor[i]  = excl;
  }
}

__global__ void k_scatter(const int* __restrict__ dst, const int* __restrict__ src,
                          int* __restrict__ cursor, int2* __restrict__ epack, int E) {
  int e = blockIdx.x*256 + threadIdx.x;
  if (e < E) {
    int d = dst[e];
    int p = atomicAdd(&cursor[d], 1);
    epack[p] = make_int2(e, src[e]);
  }
}

// ---------------- K2: per-dst softmax + aggregation (1 wave per node) ----------------
__global__ __launch_bounds__(256) void k_aggr(
    const int2* __restrict__ epack, const int* __restrict__ offsets, const int* __restrict__ counts,
    const float* __restrict__ hf, const float* __restrict__ el, const float* __restrict__ er,
    float* __restrict__ out, float* __restrict__ a_out, int N)
{
  const int wave = threadIdx.x >> 6, lane = threadIdx.x & 63;
  const int v = blockIdx.x*4 + wave;
  if (v >= N) return;
  const int start = offsets[v];
  const int deg   = counts[v];
  const float4 er4 = *(const float4*)&er[(size_t)v*4];

  // pass 1: per-head max
  float4 m4 = make_float4(-1e30f, -1e30f, -1e30f, -1e30f);
  for (int j = lane; j < deg; j += 64) {
    int2 pr = epack[start + j];
    float4 el4 = *(const float4*)&el[(size_t)pr.y*4];
    m4.x = fmaxf(m4.x, leaky(el4.x + er4.x));
    m4.y = fmaxf(m4.y, leaky(el4.y + er4.y));
    m4.z = fmaxf(m4.z, leaky(el4.z + er4.z));
    m4.w = fmaxf(m4.w, leaky(el4.w + er4.w));
  }
  #pragma unroll
  for (int mm = 32; mm; mm >>= 1) {
    m4.x = fmaxf(m4.x, __shfl_xor(m4.x, mm));
    m4.y = fmaxf(m4.y, __shfl_xor(m4.y, mm));
    m4.z = fmaxf(m4.z, __shfl_xor(m4.z, mm));
    m4.w = fmaxf(m4.w, __shfl_xor(m4.w, mm));
  }
  // pass 2: per-head sum of exp
  float4 s4 = make_float4(0.f, 0.f, 0.f, 0.f);
  for (int j = lane; j < deg; j += 64) {
    int2 pr = epack[start + j];
    float4 el4 = *(const float4*)&el[(size_t)pr.y*4];
    s4.x += __expf(leaky(el4.x + er4.x) - m4.x);
    s4.y += __expf(leaky(el4.y + er4.y) - m4.y);
    s4.z += __expf(leaky(el4.z + er4.z) - m4.z);
    s4.w += __expf(leaky(el4.w + er4.w) - m4.w);
  }
  #pragma unroll
  for (int mm = 32; mm; mm >>= 1) {
    s4.x += __shfl_xor(s4.x, mm);
    s4.y += __shfl_xor(s4.y, mm);
    s4.z += __shfl_xor(s4.z, mm);
    s4.w += __shfl_xor(s4.w, mm);
  }
  float4 r4 = make_float4(1.f/s4.x, 1.f/s4.y, 1.f/s4.z, 1.f/s4.w);

  // pass 3: write normalized attention (original edge order)
  for (int j = lane; j < deg; j += 64) {
    int2 pr = epack[start + j];
    float4 el4 = *(const float4*)&el[(size_t)pr.y*4];
    float4 a4;
    a4.x = __expf(leaky(el4.x + er4.x) - m4.x) * r4.x;
    a4.y = __expf(leaky(el4.y + er4.y) - m4.y) * r4.y;
    a4.z = __expf(leaky(el4.z + er4.z) - m4.z) * r4.z;
    a4.w = __expf(leaky(el4.w + er4.w) - m4.w) * r4.w;
    *(float4*)&a_out[(size_t)pr.x*4] = a4;
  }

  // pass 4: aggregate. lane owns features 2*lane, 2*lane+1 ; head = lane>>4
  const int head = lane >> 4;
  const float mh = sel4(m4, head), rh = sel4(r4, head), erh = sel4(er4, head);
  float accx = 0.f, accy = 0.f;
  for (int j = 0; j < deg; ++j) {
    int2 pr = epack[start + j];                       // wave-uniform
    float4 el4v = *(const float4*)&el[(size_t)pr.y*4];
    float a = __expf(leaky(sel4(el4v, head) + erh) - mh) * rh;
    float2 hv = *(const float2*)&hf[(size_t)pr.y*128 + 2*lane];
    accx += a*hv.x; accy += a*hv.y;
  }
  *(float2*)&out[(size_t)v*128 + 2*lane] = make_float2(accx, accy);
}

extern "C" void kernel_launch(void* const* d_in, const int* in_sizes, int n_in,
                              void* d_out, int out_size, void* d_ws, size_t ws_size,
                              hipStream_t stream) {
  const float* h      = (const float*)d_in[0];
  const float* fcw    = (const float*)d_in[1];
  const float* attn_l = (const float*)d_in[2];
  const float* attn_r = (const float*)d_in[3];
  const int*   src    = (const int*)d_in[4];
  const int*   dst    = (const int*)d_in[5];
  const int N = in_sizes[0] / 128;
  const int E = in_sizes[4];

  float* out   = (float*)d_out;
  float* a_out = out + (size_t)N*128;

  char* w = (char*)d_ws;
  float* hf      = (float*)w; w += (size_t)N*128*sizeof(float);
  float* el      = (float*)w; w += (size_t)N*4*sizeof(float);
  float* er      = (float*)w; w += (size_t)N*4*sizeof(float);
  int2*  epack   = (int2*)w;  w += (size_t)E*sizeof(int2);
  int*   counts  = (int*)w;   w += (size_t)N*sizeof(int);
  int*   offsets = (int*)w;   w += (size_t)N*sizeof(int);
  int*   cursor  = (int*)w;   w += (size_t)N*sizeof(int);
  int*   bsum    = (int*)w;   w += 256*sizeof(int);

  hipMemsetAsync(counts, 0, (size_t)N*sizeof(int), stream);

  dim3 gproj((N + 63)/64, 2);
  k_proj<<<gproj, 256, 0, stream>>>(h, fcw, attn_l, attn_r, hf, el, er, N);

  int ebl = (E + 255)/256;
  k_hist<<<ebl, 256, 0, stream>>>(dst, counts, E);

  int NB = (N + 255)/256;
  k_block_sums<<<NB, 256, 0, stream>>>(counts, N, bsum);
  k_scan_partials<<<1, 256, 0, stream>>>(bsum, NB);
  k_scan_chunks<<<NB, 256, 0, stream>>>(counts, N, bsum, offsets, cursor);

  k_scatter<<<ebl, 256, 0, stream>>>(dst, src, cursor, epack, E);

  k_aggr<<<(N + 3)/4, 256, 0, stream>>>(epack, offsets, counts, hf, el, er, out, a_out, N);
}

// Round 2
// 237.473 us; speedup vs baseline: 1.1417x; 1.1417x over previous
//
#include <hip/hip_runtime.h>

#define NEG 0.2f

__device__ __forceinline__ float leaky(float x){ return x > 0.f ? x : NEG*x; }
__device__ __forceinline__ float sel4(float4 q, int head){
  float lo = (head & 1) ? q.y : q.x;
  float hi = (head & 1) ? q.w : q.z;
  return (head & 2) ? hi : lo;
}

// ---------------- K1: hf = h @ fcw^T (fp32), fused el/er ----------------
// grid.x = ceil(N/64) node groups, grid.y = 2 feature halves. 256 threads.
// LDS: fc half [64 feats][128 k] (quad-XOR-swizzled) + 4 waves * 16 h rows.
__global__ __launch_bounds__(256) void k_proj(
    const float* __restrict__ h, const float* __restrict__ fcw,
    const float* __restrict__ attn_l, const float* __restrict__ attn_r,
    float* __restrict__ hf, float* __restrict__ el, float* __restrict__ er, int N)
{
  __shared__ float fcs[64][128];
  __shared__ float hs[4][16][128];
  const int g = blockIdx.y;
  const int tid = threadIdx.x;
  for (int i = tid; i < 64*32; i += 256) {
    int f = i >> 5, q = i & 31;
    float4 w = *(const float4*)&fcw[(size_t)(g*64 + f)*128 + 4*q];
    *(float4*)&fcs[f][4*(q ^ ((f>>2)&7))] = w;
  }
  const int wave = tid >> 6, lane = tid & 63;
  const int fq = lane & 15, ng = lane >> 4;
  const int nb0 = blockIdx.x*64 + wave*16;
  for (int t = lane; t < 16*32; t += 64) {
    int n = t >> 5, c = t & 31;
    int gn = nb0 + n; if (gn >= N) gn = N-1;
    *(float4*)&hs[wave][n][4*c] = *(const float4*)&h[(size_t)gn*128 + 4*c];
  }
  __syncthreads();

  float acc[4][4];
  #pragma unroll
  for (int j = 0; j < 4; ++j)
    #pragma unroll
    for (int i = 0; i < 4; ++i) acc[j][i] = 0.f;

  #pragma unroll 8
  for (int kk = 0; kk < 32; ++kk) {
    const int qc = 4*(kk ^ (fq & 7));
    float4 r0 = *(const float4*)&fcs[4*fq + 0][qc];
    float4 r1 = *(const float4*)&fcs[4*fq + 1][qc];
    float4 r2 = *(const float4*)&fcs[4*fq + 2][qc];
    float4 r3 = *(const float4*)&fcs[4*fq + 3][qc];
    #pragma unroll
    for (int j = 0; j < 4; ++j) {
      float4 hv = *(const float4*)&hs[wave][ng*4 + j][4*kk];
      acc[j][0] += hv.x*r0.x + hv.y*r0.y + hv.z*r0.z + hv.w*r0.w;
      acc[j][1] += hv.x*r1.x + hv.y*r1.y + hv.z*r1.z + hv.w*r1.w;
      acc[j][2] += hv.x*r2.x + hv.y*r2.y + hv.z*r2.z + hv.w*r2.w;
      acc[j][3] += hv.x*r3.x + hv.y*r3.y + hv.z*r3.z + hv.w*r3.w;
    }
  }

  const float4 al4 = *(const float4*)&attn_l[g*64 + 4*fq];
  const float4 ar4 = *(const float4*)&attn_r[g*64 + 4*fq];
  #pragma unroll
  for (int j = 0; j < 4; ++j) {
    int gn = nb0 + ng*4 + j;
    float4 o = make_float4(acc[j][0], acc[j][1], acc[j][2], acc[j][3]);
    float elp = o.x*al4.x + o.y*al4.y + o.z*al4.z + o.w*al4.w;
    float erp = o.x*ar4.x + o.y*ar4.y + o.z*ar4.z + o.w*ar4.w;
    elp += __shfl_xor(elp, 1); elp += __shfl_xor(elp, 2); elp += __shfl_xor(elp, 4);
    erp += __shfl_xor(erp, 1); erp += __shfl_xor(erp, 2); erp += __shfl_xor(erp, 4);
    if (gn < N) {
      *(float4*)&hf[(size_t)gn*128 + g*64 + 4*fq] = o;
      if ((lane & 7) == 0) {
        int head = g*2 + ((lane >> 3) & 1);
        el[(size_t)gn*4 + head] = elp;
        er[(size_t)gn*4 + head] = erp;
      }
    }
  }
}

// ---------------- CSR build ----------------
__global__ void k_hist(const int* __restrict__ dst, int* __restrict__ counts, int E) {
  int e = blockIdx.x*256 + threadIdx.x;
  if (e < E) atomicAdd(&counts[dst[e]], 1);
}

__global__ __launch_bounds__(256) void k_block_sums(const int* __restrict__ counts, int N, int* __restrict__ bsum) {
  __shared__ int tmp[256];
  int i = blockIdx.x*256 + threadIdx.x;
  tmp[threadIdx.x] = (i < N) ? counts[i] : 0;
  __syncthreads();
  for (int off = 128; off > 0; off >>= 1) {
    if (threadIdx.x < off) tmp[threadIdx.x] += tmp[threadIdx.x + off];
    __syncthreads();
  }
  if (threadIdx.x == 0) bsum[blockIdx.x] = tmp[0];
}

__global__ __launch_bounds__(256) void k_scan_partials(int* __restrict__ bsum, int nb) {
  __shared__ int tmp[256];
  int t = threadIdx.x;
  int v = (t < nb) ? bsum[t] : 0;
  tmp[t] = v;
  __syncthreads();
  for (int off = 1; off < 256; off <<= 1) {
    int x = (t >= off) ? tmp[t - off] : 0;
    __syncthreads();
    tmp[t] += x;
    __syncthreads();
  }
  if (t < nb) bsum[t] = tmp[t] - v;   // exclusive prefix of block sums
}

__global__ __launch_bounds__(256) void k_scan_chunks(const int* __restrict__ counts, int N,
    const int* __restrict__ bsum, int* __restrict__ offsets, int* __restrict__ cursor) {
  __shared__ int tmp[256];
  int t = threadIdx.x;
  int i = blockIdx.x*256 + t;
  int v = (i < N) ? counts[i] : 0;
  tmp[t] = v;
  __syncthreads();
  for (int off = 1; off < 256; off <<= 1) {
    int x = (t >= off) ? tmp[t - off] : 0;
    __syncthreads();
    tmp[t] += x;
    __syncthreads();
  }
  if (i < N) {
    int excl = tmp[t] - v + bsum[blockIdx.x];
    offsets[i] = excl;
    cursor[i]  = excl;
  }
}

__global__ void k_scatter(const int* __restrict__ dst, const int* __restrict__ src,
                          int* __restrict__ cursor, int2* __restrict__ epack, int E) {
  int e = blockIdx.x*256 + threadIdx.x;
  if (e < E) {
    int d = dst[e];
    int p = atomicAdd(&cursor[d], 1);
    epack[p] = make_int2(e, src[e]);
  }
}

// ---------------- K2: per-dst softmax + aggregation (1 wave per node) ----------------
// pass A: fused max+sum (deg<=64 fast path: single el gather kept in regs)
// pass B: fused a_out write + aggregation, 4 edges in flight
//         (group g = lane>>4 owns edge j+g; sublane l = lane&15 owns feats 8l..8l+7)
__global__ __launch_bounds__(256) void k_aggr(
    const int2* __restrict__ epack, const int* __restrict__ offsets, const int* __restrict__ counts,
    const float* __restrict__ hf, const float* __restrict__ el, const float* __restrict__ er,
    float* __restrict__ out, float* __restrict__ a_out, int N)
{
  const int wave = threadIdx.x >> 6, lane = threadIdx.x & 63;
  const int v = blockIdx.x*4 + wave;
  if (v >= N) return;
  const int start = offsets[v];
  const int deg   = counts[v];
  const float4 er4 = *(const float4*)&er[(size_t)v*4];

  // ---- pass A: per-head max and exp-sum, one gather for deg<=64 ----
  const bool act = lane < deg;
  float4 e4 = make_float4(-1e30f, -1e30f, -1e30f, -1e30f);
  if (act) {
    int2 pr = epack[start + lane];
    float4 el4 = *(const float4*)&el[(size_t)pr.y*4];
    e4.x = leaky(el4.x + er4.x);
    e4.y = leaky(el4.y + er4.y);
    e4.z = leaky(el4.z + er4.z);
    e4.w = leaky(el4.w + er4.w);
  }
  float4 m4 = e4;
  for (int j = lane + 64; j < deg; j += 64) {   // rare (deg>64) spill loop
    int2 pr = epack[start + j];
    float4 el4 = *(const float4*)&el[(size_t)pr.y*4];
    m4.x = fmaxf(m4.x, leaky(el4.x + er4.x));
    m4.y = fmaxf(m4.y, leaky(el4.y + er4.y));
    m4.z = fmaxf(m4.z, leaky(el4.z + er4.z));
    m4.w = fmaxf(m4.w, leaky(el4.w + er4.w));
  }
  #pragma unroll
  for (int mm = 32; mm; mm >>= 1) {
    m4.x = fmaxf(m4.x, __shfl_xor(m4.x, mm));
    m4.y = fmaxf(m4.y, __shfl_xor(m4.y, mm));
    m4.z = fmaxf(m4.z, __shfl_xor(m4.z, mm));
    m4.w = fmaxf(m4.w, __shfl_xor(m4.w, mm));
  }
  float4 s4 = make_float4(0.f, 0.f, 0.f, 0.f);
  if (act) {
    s4.x = __expf(e4.x - m4.x);
    s4.y = __expf(e4.y - m4.y);
    s4.z = __expf(e4.z - m4.z);
    s4.w = __expf(e4.w - m4.w);
  }
  for (int j = lane + 64; j < deg; j += 64) {   // rare
    int2 pr = epack[start + j];
    float4 el4 = *(const float4*)&el[(size_t)pr.y*4];
    s4.x += __expf(leaky(el4.x + er4.x) - m4.x);
    s4.y += __expf(leaky(el4.y + er4.y) - m4.y);
    s4.z += __expf(leaky(el4.z + er4.z) - m4.z);
    s4.w += __expf(leaky(el4.w + er4.w) - m4.w);
  }
  #pragma unroll
  for (int mm = 32; mm; mm >>= 1) {
    s4.x += __shfl_xor(s4.x, mm);
    s4.y += __shfl_xor(s4.y, mm);
    s4.z += __shfl_xor(s4.z, mm);
    s4.w += __shfl_xor(s4.w, mm);
  }
  float4 r4 = make_float4(1.f/s4.x, 1.f/s4.y, 1.f/s4.z, 1.f/s4.w);

  // ---- pass B: a_out + aggregation, 4 edges in flight ----
  const int g = lane >> 4;          // edge slot within wave
  const int l = lane & 15;          // feature sublane: feats 8l..8l+7
  const int head = l >> 2;
  const float mh  = sel4(m4, head);
  const float rh  = sel4(r4, head);
  const float erh = sel4(er4, head);
  float acc[8];
  #pragma unroll
  for (int k = 0; k < 8; ++k) acc[k] = 0.f;

  for (int j = 0; j < deg; j += 4) {
    const int je = j + g;
    const bool valid = je < deg;
    int2 pr = epack[start + (valid ? je : 0)];
    float a = __expf(leaky(el[(size_t)pr.y*4 + head] + erh) - mh) * rh;
    if (!valid) a = 0.f;
    if (valid && (l & 3) == 0) a_out[(size_t)pr.x*4 + head] = a;
    const float* hrow = &hf[(size_t)pr.y*128 + 8*l];
    float4 h0 = *(const float4*)hrow;
    float4 h1 = *(const float4*)(hrow + 4);
    acc[0] += a*h0.x; acc[1] += a*h0.y; acc[2] += a*h0.z; acc[3] += a*h0.w;
    acc[4] += a*h1.x; acc[5] += a*h1.y; acc[6] += a*h1.z; acc[7] += a*h1.w;
  }
  #pragma unroll
  for (int k = 0; k < 8; ++k) {
    acc[k] += __shfl_xor(acc[k], 16);
    acc[k] += __shfl_xor(acc[k], 32);
  }
  if (g == 0) {
    *(float4*)&out[(size_t)v*128 + 8*l]     = make_float4(acc[0], acc[1], acc[2], acc[3]);
    *(float4*)&out[(size_t)v*128 + 8*l + 4] = make_float4(acc[4], acc[5], acc[6], acc[7]);
  }
}

extern "C" void kernel_launch(void* const* d_in, const int* in_sizes, int n_in,
                              void* d_out, int out_size, void* d_ws, size_t ws_size,
                              hipStream_t stream) {
  const float* h      = (const float*)d_in[0];
  const float* fcw    = (const float*)d_in[1];
  const float* attn_l = (const float*)d_in[2];
  const float* attn_r = (const float*)d_in[3];
  const int*   src    = (const int*)d_in[4];
  const int*   dst    = (const int*)d_in[5];
  const int N = in_sizes[0] / 128;
  const int E = in_sizes[4];

  float* out   = (float*)d_out;
  float* a_out = out + (size_t)N*128;

  char* w = (char*)d_ws;
  float* hf      = (float*)w; w += (size_t)N*128*sizeof(float);
  float* el      = (float*)w; w += (size_t)N*4*sizeof(float);
  float* er      = (float*)w; w += (size_t)N*4*sizeof(float);
  int2*  epack   = (int2*)w;  w += (size_t)E*sizeof(int2);
  int*   counts  = (int*)w;   w += (size_t)N*sizeof(int);
  int*   offsets = (int*)w;   w += (size_t)N*sizeof(int);
  int*   cursor  = (int*)w;   w += (size_t)N*sizeof(int);
  int*   bsum    = (int*)w;   w += 256*sizeof(int);

  hipMemsetAsync(counts, 0, (size_t)N*sizeof(int), stream);

  dim3 gproj((N + 63)/64, 2);
  k_proj<<<gproj, 256, 0, stream>>>(h, fcw, attn_l, attn_r, hf, el, er, N);

  int ebl = (E + 255)/256;
  k_hist<<<ebl, 256, 0, stream>>>(dst, counts, E);

  int NB = (N + 255)/256;
  k_block_sums<<<NB, 256, 0, stream>>>(counts, N, bsum);
  k_scan_partials<<<1, 256, 0, stream>>>(bsum, NB);
  k_scan_chunks<<<NB, 256, 0, stream>>>(counts, N, bsum, offsets, cursor);

  k_scatter<<<ebl, 256, 0, stream>>>(dst, src, cursor, epack, E);

  k_aggr<<<(N + 3)/4, 256, 0, stream>>>(epack, offsets, counts, hf, el, er, out, a_out, N);
}